// Round 2
// baseline (903.447 us; speedup 1.0000x reference)
//
#include <hip/hip_runtime.h>
#include <cmath>

typedef __bf16 bf16x8 __attribute__((ext_vector_type(8)));
typedef float  f32x4  __attribute__((ext_vector_type(4)));

#define MFMA16(a,b,c) __builtin_amdgcn_mfma_f32_16x16x32_bf16((a),(b),(c),0,0,0)

// DIM=96 NH=3 HEAD=32 WS=7 SHIFT=3 P=5 H=W=56 NWH=NWW=8 NW=64 TP=320 N=54 HIDDEN=384 B=64
// tokens/batch = 3456, windows total = 64*64 = 4096, token rows total = 221184
#define SCALE_Q 0.17677669529663687f   // 32^-0.5

// ---------------- weight convert: fp32 -> bf16, transposed to [n][k] ----------------
// ws layout (bf16 elements): qkvT [288][96] @0 | projT [96][96] @27648 | fc1T [384][96] @36864 | fc2T [96][384] @73728
__global__ __launch_bounds__(256) void wconv(const float* __restrict__ qkv_w,
                                             const float* __restrict__ proj_w,
                                             const float* __restrict__ fc1_w,
                                             const float* __restrict__ fc2_w,
                                             __bf16* __restrict__ ws)
{
    int i = blockIdx.x * 256 + threadIdx.x;
    if (i < 27648) {                       // qkv_w (96,288) -> [c][k], fold q-scale
        int c = i / 96, k = i % 96;
        float v = qkv_w[k * 288 + c];
        if (c < 96) v *= SCALE_Q;
        ws[i] = (__bf16)v;
        return;
    }
    i -= 27648;
    if (i < 9216) {                        // proj_w (96,96)
        int c = i / 96, k = i % 96;
        ws[27648 + i] = (__bf16)proj_w[k * 96 + c];
        return;
    }
    i -= 9216;
    if (i < 36864) {                       // fc1_w (96,384)
        int c = i / 96, k = i % 96;
        ws[36864 + i] = (__bf16)fc1_w[k * 384 + c];
        return;
    }
    i -= 36864;
    if (i < 36864) {                       // fc2_w (384,96)
        int c = i / 384, k = i % 384;
        ws[73728 + i] = (__bf16)fc2_w[k * 96 + c];
    }
}

// token index in x for window token t of window (b, w=wh*8+ww); gather==scatter (roll is inverted by +SHIFT)
__device__ __forceinline__ int src_index(int b, int w, int wh, int ww, int t)
{
    if (t < 5) return b * 3456 + w * 5 + t;
    int a = t - 5;
    int hi = wh * 7 + a / 7 + 3; if (hi >= 56) hi -= 56;
    int wi = ww * 7 + a % 7 + 3; if (wi >= 56) wi -= 56;
    return b * 3456 + 320 + hi * 56 + wi;
}

// ---------------- fused LN1 + window attention + proj; writes a (pre-residual) fp32 to aout ----------------
__global__ __launch_bounds__(256) void attn_fused(const float* __restrict__ x,
                                                  const float* __restrict__ n1g, const float* __restrict__ n1b,
                                                  const float* __restrict__ qkvb, const float* __restrict__ rpb,
                                                  const float* __restrict__ projb,
                                                  const __bf16* __restrict__ wqkvT, const __bf16* __restrict__ wprojT,
                                                  float* __restrict__ aout)
{
    __shared__ __align__(16) char smem[61440];
    __bf16* xn  = (__bf16*)(smem);           // [64][96]   12288 B   (dead after P2)
    __bf16* qkv = (__bf16*)(smem + 12288);   // [64][288]  36864 B   (dead after P3)
    __bf16* vT  = (__bf16*)(smem + 49152);   // [96][64]   12288 B   rows = h*32+d, cols = token m
    __bf16* Pm  = (__bf16*)(smem);           // [3][64][64] 24576 B  aliases xn + low qkv (after barrier)
    __bf16* ob  = (__bf16*)(smem + 24576);   // [64][96]   12288 B   aliases high qkv (dead)

    const int tid  = threadIdx.x;
    const int lane = tid & 63;
    const int wv   = tid >> 6;
    const int l15  = lane & 15;
    const int quad = lane >> 4;

    const int g  = blockIdx.x;
    const int b  = g >> 6;
    const int w  = g & 63;
    const int wh = w >> 3;
    const int ww = w & 7;

    // P0: zero pad rows of xn (54..63); vT is fully overwritten in P2 (no fill needed)
    for (int i = tid; i < 960; i += 256)  xn[5184 + i] = (__bf16)0.0f;

    // P1: gather + LN1 (one token per wave-iteration; 48 lanes x float2 = 96 elems)
    for (int t = wv; t < 54; t += 4) {
        int src = src_index(b, w, wh, ww, t);
        float2 v = make_float2(0.f, 0.f);
        if (lane < 48) v = *(const float2*)(x + (size_t)src * 96 + lane * 2);
        float s  = v.x + v.y;
        float sq = v.x * v.x + v.y * v.y;
        #pragma unroll
        for (int d = 1; d < 64; d <<= 1) { s += __shfl_xor(s, d, 64); sq += __shfl_xor(sq, d, 64); }
        float mean = s * (1.f / 96.f);
        float rstd = rsqrtf(sq * (1.f / 96.f) - mean * mean + 1e-5f);
        if (lane < 48) {
            int c = lane * 2;
            xn[t * 96 + c]     = (__bf16)((v.x - mean) * rstd * n1g[c] + n1b[c]);
            xn[t * 96 + c + 1] = (__bf16)((v.y - mean) * rstd * n1g[c + 1] + n1b[c + 1]);
        }
    }
    __syncthreads();

    // P2: QKV = xn(64x96) @ qkv_wT  -> qkv LDS [token][288]; v also transposed into vT
    for (int tt = wv; tt < 72; tt += 4) {
        int mt = tt & 3, nt = tt >> 2;
        const __bf16* ar = xn + (mt * 16 + l15) * 96 + quad * 8;
        const __bf16* br = wqkvT + (size_t)(nt * 16 + l15) * 96 + quad * 8;
        f32x4 acc = {0.f, 0.f, 0.f, 0.f};
        #pragma unroll
        for (int ks = 0; ks < 3; ks++)
            acc = MFMA16(*(const bf16x8*)(ar + ks * 32), *(const bf16x8*)(br + ks * 32), acc);
        int col = nt * 16 + l15;
        float bias = qkvb[col] * (col < 96 ? SCALE_Q : 1.f);
        #pragma unroll
        for (int r = 0; r < 4; r++) {
            int row = mt * 16 + quad * 4 + r;
            __bf16 bv = (__bf16)(acc[r] + bias);
            qkv[row * 288 + col] = bv;
            if (col >= 192) vT[(col - 192) * 64 + row] = bv;
        }
    }
    __syncthreads();

    // P3: scores S = q @ k^T + rel-pos bias + shift mask (kept in registers, C-layout)
    // region boundaries in rolled coords: [0,49) | [49,53) | [53,56)   (H-WS=49, H-SHIFT=53)
    float sc[3][4][4];
    #pragma unroll
    for (int p = 0; p < 3; p++) {
        int pid = wv + 4 * p;
        int h = pid >> 2, mt = pid & 3;
        bf16x8 aq = *(const bf16x8*)(qkv + (mt * 16 + l15) * 288 + h * 32 + quad * 8);
        #pragma unroll
        for (int nt = 0; nt < 4; nt++) {
            bf16x8 bk = *(const bf16x8*)(qkv + (nt * 16 + l15) * 288 + 96 + h * 32 + quad * 8);
            f32x4 c = {0.f, 0.f, 0.f, 0.f};
            c = MFMA16(aq, bk, c);
            int m = nt * 16 + l15;
            #pragma unroll
            for (int r = 0; r < 4; r++) {
                int n = mt * 16 + quad * 4 + r;
                float sv = c[r];
                if (m >= 54) {
                    sv = -1e30f;                      // padded key columns excluded from softmax
                } else if (n >= 5 && n < 54 && m >= 5) {
                    int an = n - 5, am = m - 5;
                    int iy = an / 7, ix = an % 7, jy = am / 7, jx = am % 7;
                    sv += rpb[((iy - jy + 6) * 13 + (ix - jx + 6)) * 3 + h];
                    int hn = wh * 7 + iy, wn = ww * 7 + ix;
                    int hm = wh * 7 + jy, wm = ww * 7 + jx;
                    int idn = (hn < 49 ? 0 : (hn < 53 ? 1 : 2)) * 3 + (wn < 49 ? 0 : (wn < 53 ? 1 : 2));
                    int idm = (hm < 49 ? 0 : (hm < 53 ? 1 : 2)) * 3 + (wm < 49 ? 0 : (wm < 53 ? 1 : 2));
                    if (idn != idm) sv -= 100.f;
                }
                sc[p][nt][r] = sv;
            }
        }
    }
    __syncthreads();   // all q/k reads done; Pm may now overwrite that LDS

    // P4: softmax across m (row lives in one quad: 16-lane shfl_xor reduction), write P bf16
    #pragma unroll
    for (int p = 0; p < 3; p++) {
        int pid = wv + 4 * p;
        int h = pid >> 2, mt = pid & 3;
        #pragma unroll
        for (int r = 0; r < 4; r++) {
            float mx = fmaxf(fmaxf(sc[p][0][r], sc[p][1][r]), fmaxf(sc[p][2][r], sc[p][3][r]));
            #pragma unroll
            for (int d = 1; d < 16; d <<= 1) mx = fmaxf(mx, __shfl_xor(mx, d, 16));
            float e0 = __expf(sc[p][0][r] - mx), e1 = __expf(sc[p][1][r] - mx);
            float e2 = __expf(sc[p][2][r] - mx), e3 = __expf(sc[p][3][r] - mx);
            float sum = e0 + e1 + e2 + e3;
            #pragma unroll
            for (int d = 1; d < 16; d <<= 1) sum += __shfl_xor(sum, d, 16);
            float inv = 1.f / sum;
            int row = mt * 16 + quad * 4 + r;
            __bf16* pr = Pm + (h * 64 + row) * 64 + l15;
            pr[0]  = (__bf16)(e0 * inv);
            pr[16] = (__bf16)(e1 * inv);
            pr[32] = (__bf16)(e2 * inv);
            pr[48] = (__bf16)(e3 * inv);
        }
    }
    __syncthreads();

    // P5: out = P @ V  (A = P[n][m], B = vT[d][m]) -> ob [token][96] bf16
    for (int tt = wv; tt < 24; tt += 4) {
        int h = tt >> 3, mt = (tt >> 1) & 3, dt = tt & 1;
        const __bf16* pr = Pm + (h * 64 + mt * 16 + l15) * 64 + quad * 8;
        const __bf16* vr = vT + (h * 32 + dt * 16 + l15) * 64 + quad * 8;
        f32x4 acc = {0.f, 0.f, 0.f, 0.f};
        acc = MFMA16(*(const bf16x8*)(pr), *(const bf16x8*)(vr), acc);
        acc = MFMA16(*(const bf16x8*)(pr + 32), *(const bf16x8*)(vr + 32), acc);
        int col = h * 32 + dt * 16 + l15;
        #pragma unroll
        for (int r = 0; r < 4; r++) ob[(mt * 16 + quad * 4 + r) * 96 + col] = (__bf16)acc[r];
    }
    __syncthreads();

    // P6: proj + scatter a = ob @ proj_wT + proj_b (no residual; MLP kernel adds x)
    for (int tt = wv; tt < 24; tt += 4) {
        int mt = tt & 3, nt = tt >> 2;
        const __bf16* ar = ob + (mt * 16 + l15) * 96 + quad * 8;
        const __bf16* br = wprojT + (size_t)(nt * 16 + l15) * 96 + quad * 8;
        f32x4 acc = {0.f, 0.f, 0.f, 0.f};
        #pragma unroll
        for (int ks = 0; ks < 3; ks++)
            acc = MFMA16(*(const bf16x8*)(ar + ks * 32), *(const bf16x8*)(br + ks * 32), acc);
        int col = nt * 16 + l15;
        float pb = projb[col];
        #pragma unroll
        for (int r = 0; r < 4; r++) {
            int row = mt * 16 + quad * 4 + r;
            if (row < 54) {
                int src = src_index(b, w, wh, ww, row);
                aout[(size_t)src * 96 + col] = acc[r] + pb;
            }
        }
    }
}

// ---------------- fused y = x + a; LN2; fc1+GELU; fc2; final = y + mlp (in-place on io=d_out) ----------------
__global__ __launch_bounds__(256) void mlp_fused(const float* __restrict__ x,
                                                 const float* __restrict__ n2g, const float* __restrict__ n2b,
                                                 const float* __restrict__ fc1b, const float* __restrict__ fc2b,
                                                 const __bf16* __restrict__ w1T, const __bf16* __restrict__ w2T,
                                                 float* __restrict__ io)
{
    __shared__ __align__(16) char smem[61440];
    __bf16* xn = (__bf16*)smem;             // [64][96]  12288 B
    __bf16* hb = (__bf16*)(smem + 12288);   // [64][384] 49152 B

    const int tid  = threadIdx.x;
    const int lane = tid & 63;
    const int wv   = tid >> 6;
    const int l15  = lane & 15;
    const int quad = lane >> 4;
    const size_t t0 = (size_t)blockIdx.x * 64;

    // Phase 1: y = x + a, LN2 -> xn bf16
    for (int it = 0; it < 16; it++) {
        int row = wv * 16 + it;
        size_t base = (t0 + row) * 96;
        float2 xv = make_float2(0.f, 0.f), av = make_float2(0.f, 0.f);
        if (lane < 48) {
            xv = *(const float2*)(x + base + lane * 2);
            av = *(const float2*)(io + base + lane * 2);
        }
        float y0 = xv.x + av.x, y1 = xv.y + av.y;
        float s = y0 + y1, sq = y0 * y0 + y1 * y1;
        #pragma unroll
        for (int d = 1; d < 64; d <<= 1) { s += __shfl_xor(s, d, 64); sq += __shfl_xor(sq, d, 64); }
        float mean = s * (1.f / 96.f);
        float rstd = rsqrtf(sq * (1.f / 96.f) - mean * mean + 1e-5f);
        if (lane < 48) {
            int c = lane * 2;
            xn[row * 96 + c]     = (__bf16)((y0 - mean) * rstd * n2g[c] + n2b[c]);
            xn[row * 96 + c + 1] = (__bf16)((y1 - mean) * rstd * n2g[c + 1] + n2b[c + 1]);
        }
    }
    __syncthreads();

    // Phase 2: h = gelu(xn @ fc1_wT + fc1_b) -> hb bf16 (wave owns column-tiles, no redundant B loads)
    bf16x8 afr[4][3];
    #pragma unroll
    for (int mt = 0; mt < 4; mt++)
        #pragma unroll
        for (int ks = 0; ks < 3; ks++)
            afr[mt][ks] = *(const bf16x8*)(xn + (mt * 16 + l15) * 96 + ks * 32 + quad * 8);

    for (int nt = wv; nt < 24; nt += 4) {
        f32x4 z = {0.f, 0.f, 0.f, 0.f};
        f32x4 acc[4] = {z, z, z, z};
        const __bf16* br = w1T + (size_t)(nt * 16 + l15) * 96 + quad * 8;
        #pragma unroll
        for (int ks = 0; ks < 3; ks++) {
            bf16x8 bf = *(const bf16x8*)(br + ks * 32);
            #pragma unroll
            for (int mt = 0; mt < 4; mt++) acc[mt] = MFMA16(afr[mt][ks], bf, acc[mt]);
        }
        int col = nt * 16 + l15;
        float fb = fc1b[col];
        #pragma unroll
        for (int mt = 0; mt < 4; mt++)
            #pragma unroll
            for (int r = 0; r < 4; r++) {
                float v = acc[mt][r] + fb;
                float ge = 0.5f * v * (1.f + erff(v * 0.7071067811865475f));
                hb[(mt * 16 + quad * 4 + r) * 384 + col] = (__bf16)ge;
            }
    }
    __syncthreads();

    // Phase 3: out = y + hb @ fc2_wT + fc2_b ; y recomputed as x + a (both L2-hot), in-place store
    for (int nt = wv; nt < 6; nt += 4) {
        int col = nt * 16 + l15;
        float fb = fc2b[col];
        const __bf16* br = w2T + (size_t)col * 384 + quad * 8;
        for (int mt = 0; mt < 4; mt++) {
            const __bf16* ar = hb + (mt * 16 + l15) * 384 + quad * 8;
            f32x4 acc = {0.f, 0.f, 0.f, 0.f};
            #pragma unroll
            for (int ks = 0; ks < 12; ks++)
                acc = MFMA16(*(const bf16x8*)(ar + ks * 32), *(const bf16x8*)(br + ks * 32), acc);
            #pragma unroll
            for (int r = 0; r < 4; r++) {
                int row = mt * 16 + quad * 4 + r;
                size_t ad = (t0 + row) * 96 + col;
                io[ad] = acc[r] + fb + x[ad] + io[ad];
            }
        }
    }
}

extern "C" void kernel_launch(void* const* d_in, const int* in_sizes, int n_in,
                              void* d_out, int out_size, void* d_ws, size_t ws_size,
                              hipStream_t stream)
{
    const float* x      = (const float*)d_in[0];
    const float* n1g    = (const float*)d_in[1];
    const float* n1b    = (const float*)d_in[2];
    const float* qkv_w  = (const float*)d_in[3];
    const float* qkv_b  = (const float*)d_in[4];
    const float* rpb    = (const float*)d_in[5];
    const float* proj_w = (const float*)d_in[6];
    const float* proj_b = (const float*)d_in[7];
    const float* n2g    = (const float*)d_in[8];
    const float* n2b    = (const float*)d_in[9];
    const float* fc1_w  = (const float*)d_in[10];
    const float* fc1_b  = (const float*)d_in[11];
    const float* fc2_w  = (const float*)d_in[12];
    const float* fc2_b  = (const float*)d_in[13];

    __bf16* ws     = (__bf16*)d_ws;
    __bf16* wqkvT  = ws;            // [288][96]
    __bf16* wprojT = ws + 27648;    // [96][96]
    __bf16* w1T    = ws + 36864;    // [384][96]
    __bf16* w2T    = ws + 73728;    // [96][384]

    float* out = (float*)d_out;

    hipLaunchKernelGGL(wconv, dim3(432), dim3(256), 0, stream, qkv_w, proj_w, fc1_w, fc2_w, ws);
    hipLaunchKernelGGL(attn_fused, dim3(4096), dim3(256), 0, stream,
                       x, n1g, n1b, qkv_b, rpb, proj_b, wqkvT, wprojT, out);
    hipLaunchKernelGGL(mlp_fused, dim3(3456), dim3(256), 0, stream,
                       x, n2g, n2b, fc1_b, fc2_b, w1T, w2T, out);
}

// Round 3
// 701.810 us; speedup vs baseline: 1.2873x; 1.2873x over previous
//
#include <hip/hip_runtime.h>
#include <cmath>

typedef __bf16 bf16x8 __attribute__((ext_vector_type(8)));
typedef float  f32x4  __attribute__((ext_vector_type(4)));

#define MFMA16(a,b,c) __builtin_amdgcn_mfma_f32_16x16x32_bf16((a),(b),(c),0,0,0)

// DIM=96 NH=3 HEAD=32 WS=7 SHIFT=3 P=5 H=W=56 NWH=NWW=8 NW=64 TP=320 N=54 HIDDEN=384 B=64
#define SCALE_Q 0.17677669529663687f   // 32^-0.5

// LDS paddings chosen so row-stride(dwords) % 32 == 20 (or 4) -> <=2-way conflicts on b128 reads
#define XP 104   // xn/ob row pad (bf16): 208 B = 52 dw, 52%32=20
#define QP 296   // qkv row pad: 592 B = 148 dw, %32=20
#define VP 72    // vT/Pm row pad: 144 B = 36 dw, %32=4

// ---------------- weight convert: fp32 -> bf16, transposed to [n][k] ----------------
__global__ __launch_bounds__(256) void wconv(const float* __restrict__ qkv_w,
                                             const float* __restrict__ proj_w,
                                             const float* __restrict__ fc1_w,
                                             const float* __restrict__ fc2_w,
                                             __bf16* __restrict__ ws)
{
    int i = blockIdx.x * 256 + threadIdx.x;
    if (i < 27648) {                       // qkv_w (96,288) -> [c][k], fold q-scale
        int c = i / 96, k = i % 96;
        float v = qkv_w[k * 288 + c];
        if (c < 96) v *= SCALE_Q;
        ws[i] = (__bf16)v;
        return;
    }
    i -= 27648;
    if (i < 9216) {                        // proj_w (96,96)
        int c = i / 96, k = i % 96;
        ws[27648 + i] = (__bf16)proj_w[k * 96 + c];
        return;
    }
    i -= 9216;
    if (i < 36864) {                       // fc1_w (96,384)
        int c = i / 96, k = i % 96;
        ws[36864 + i] = (__bf16)fc1_w[k * 384 + c];
        return;
    }
    i -= 36864;
    if (i < 36864) {                       // fc2_w (384,96)
        int c = i / 384, k = i % 384;
        ws[73728 + i] = (__bf16)fc2_w[k * 96 + c];
    }
}

// token index in x for window token t of window (b, w=wh*8+ww); gather==scatter
__device__ __forceinline__ int src_index(int b, int w, int wh, int ww, int t)
{
    if (t < 5) return b * 3456 + w * 5 + t;
    int a = t - 5;
    int hi = wh * 7 + a / 7 + 3; if (hi >= 56) hi -= 56;
    int wi = ww * 7 + a % 7 + 3; if (wi >= 56) wi -= 56;
    return b * 3456 + 320 + hi * 56 + wi;
}

// ---------------- fused LN1 + window attention + proj; writes a (pre-residual) fp32 ----------------
__global__ __launch_bounds__(256, 2) void attn_fused(const float* __restrict__ x,
                                                  const float* __restrict__ n1g, const float* __restrict__ n1b,
                                                  const float* __restrict__ qkvb, const float* __restrict__ rpb,
                                                  const float* __restrict__ projb,
                                                  const __bf16* __restrict__ wqkvT, const __bf16* __restrict__ wprojT,
                                                  float* __restrict__ aout)
{
    __shared__ __align__(16) char smem[65024];
    __bf16* xn  = (__bf16*)(smem);           // [64][XP]   13312 B  (dead after P2)
    __bf16* qkv = (__bf16*)(smem + 13312);   // [64][QP]   37888 B  (dead after P3)
    __bf16* vT  = (__bf16*)(smem + 51200);   // [96][VP]   13824 B
    __bf16* Pm  = (__bf16*)(smem);           // [3][64][VP] 27648 B  aliases xn+qkv-head (after P3 barrier)
    __bf16* ob  = (__bf16*)(smem + 27648);   // [64][XP]   13312 B  aliases dead qkv tail

    const int tid  = threadIdx.x;
    const int lane = tid & 63;
    const int wv   = tid >> 6;
    const int l15  = lane & 15;
    const int quad = lane >> 4;

    const int g  = blockIdx.x;
    const int b  = g >> 6;
    const int w  = g & 63;
    const int wh = w >> 3;
    const int ww = w & 7;

    // P0: zero pad rows 54..63 of xn (so qkv/vT rows >=54 stay finite)
    for (int i = tid; i < 1040; i += 256) xn[54 * XP + i] = (__bf16)0.0f;

    // P1: gather + LN1, 4 tokens per wave-iteration (16-lane groups, 6 elems/lane)
    {
        const int c0 = l15 * 6;
        float g0 = n1g[c0], g1 = n1g[c0+1], g2 = n1g[c0+2], g3 = n1g[c0+3], g4 = n1g[c0+4], g5 = n1g[c0+5];
        float b0 = n1b[c0], b1 = n1b[c0+1], b2 = n1b[c0+2], b3 = n1b[c0+3], b4 = n1b[c0+4], b5 = n1b[c0+5];
        #pragma unroll
        for (int it = 0; it < 4; it++) {
            int t = it * 16 + wv * 4 + quad;
            if (t < 54) {
                int src = src_index(b, w, wh, ww, t);
                const float* xr = x + (size_t)src * 96 + c0;
                float2 v0 = *(const float2*)(xr);
                float2 v1 = *(const float2*)(xr + 2);
                float2 v2 = *(const float2*)(xr + 4);
                float s  = v0.x + v0.y + v1.x + v1.y + v2.x + v2.y;
                float sq = v0.x*v0.x + v0.y*v0.y + v1.x*v1.x + v1.y*v1.y + v2.x*v2.x + v2.y*v2.y;
                #pragma unroll
                for (int d = 1; d < 16; d <<= 1) { s += __shfl_xor(s, d, 16); sq += __shfl_xor(sq, d, 16); }
                float mean = s * (1.f / 96.f);
                float rstd = rsqrtf(sq * (1.f / 96.f) - mean * mean + 1e-5f);
                __bf16* xr2 = xn + t * XP + c0;
                xr2[0] = (__bf16)((v0.x - mean) * rstd * g0 + b0);
                xr2[1] = (__bf16)((v0.y - mean) * rstd * g1 + b1);
                xr2[2] = (__bf16)((v1.x - mean) * rstd * g2 + b2);
                xr2[3] = (__bf16)((v1.y - mean) * rstd * g3 + b3);
                xr2[4] = (__bf16)((v2.x - mean) * rstd * g4 + b4);
                xr2[5] = (__bf16)((v2.y - mean) * rstd * g5 + b5);
            }
        }
    }
    __syncthreads();

    // P2: QKV = xn(64x96) @ qkv_wT -> qkv [token][QP]; v also transposed into vT
    for (int tt = wv; tt < 72; tt += 4) {
        int mt = tt & 3, nt = tt >> 2;
        const __bf16* ar = xn + (mt * 16 + l15) * XP + quad * 8;
        const __bf16* br = wqkvT + (size_t)(nt * 16 + l15) * 96 + quad * 8;
        f32x4 acc = {0.f, 0.f, 0.f, 0.f};
        #pragma unroll
        for (int ks = 0; ks < 3; ks++)
            acc = MFMA16(*(const bf16x8*)(ar + ks * 32), *(const bf16x8*)(br + ks * 32), acc);
        int col = nt * 16 + l15;
        float bias = qkvb[col] * (col < 96 ? SCALE_Q : 1.f);
        #pragma unroll
        for (int r = 0; r < 4; r++) {
            int row = mt * 16 + quad * 4 + r;
            __bf16 bv = (__bf16)(acc[r] + bias);
            qkv[row * QP + col] = bv;
            if (col >= 192) vT[(col - 192) * VP + row] = bv;
        }
    }
    __syncthreads();

    // P3: scores S = q @ k^T + rel-pos bias + shift mask (registers, C-layout)
    // region boundaries in rolled coords: [0,49) | [49,53) | [53,56)
    float sc[3][4][4];
    #pragma unroll
    for (int p = 0; p < 3; p++) {
        int pid = wv + 4 * p;
        int h = pid >> 2, mt = pid & 3;
        bf16x8 aq = *(const bf16x8*)(qkv + (mt * 16 + l15) * QP + h * 32 + quad * 8);
        #pragma unroll
        for (int nt = 0; nt < 4; nt++) {
            bf16x8 bk = *(const bf16x8*)(qkv + (nt * 16 + l15) * QP + 96 + h * 32 + quad * 8);
            f32x4 c = {0.f, 0.f, 0.f, 0.f};
            c = MFMA16(aq, bk, c);
            int m = nt * 16 + l15;
            #pragma unroll
            for (int r = 0; r < 4; r++) {
                int n = mt * 16 + quad * 4 + r;
                float sv = c[r];
                if (m >= 54) {
                    sv = -1e30f;
                } else if (n >= 5 && n < 54 && m >= 5) {
                    int an = n - 5, am = m - 5;
                    int iy = an / 7, ix = an % 7, jy = am / 7, jx = am % 7;
                    sv += rpb[((iy - jy + 6) * 13 + (ix - jx + 6)) * 3 + h];
                    int hn = wh * 7 + iy, wn = ww * 7 + ix;
                    int hm = wh * 7 + jy, wm = ww * 7 + jx;
                    int idn = (hn < 49 ? 0 : (hn < 53 ? 1 : 2)) * 3 + (wn < 49 ? 0 : (wn < 53 ? 1 : 2));
                    int idm = (hm < 49 ? 0 : (hm < 53 ? 1 : 2)) * 3 + (wm < 49 ? 0 : (wm < 53 ? 1 : 2));
                    if (idn != idm) sv -= 100.f;
                }
                sc[p][nt][r] = sv;
            }
        }
    }
    __syncthreads();   // q/k reads done; Pm may overwrite

    // P4: softmax across m (row in one quad-group), write P bf16
    #pragma unroll
    for (int p = 0; p < 3; p++) {
        int pid = wv + 4 * p;
        int h = pid >> 2, mt = pid & 3;
        #pragma unroll
        for (int r = 0; r < 4; r++) {
            float mx = fmaxf(fmaxf(sc[p][0][r], sc[p][1][r]), fmaxf(sc[p][2][r], sc[p][3][r]));
            #pragma unroll
            for (int d = 1; d < 16; d <<= 1) mx = fmaxf(mx, __shfl_xor(mx, d, 16));
            float e0 = __expf(sc[p][0][r] - mx), e1 = __expf(sc[p][1][r] - mx);
            float e2 = __expf(sc[p][2][r] - mx), e3 = __expf(sc[p][3][r] - mx);
            float sum = e0 + e1 + e2 + e3;
            #pragma unroll
            for (int d = 1; d < 16; d <<= 1) sum += __shfl_xor(sum, d, 16);
            float inv = 1.f / sum;
            int row = mt * 16 + quad * 4 + r;
            __bf16* pr = Pm + (h * 64 + row) * VP + l15;
            pr[0]  = (__bf16)(e0 * inv);
            pr[16] = (__bf16)(e1 * inv);
            pr[32] = (__bf16)(e2 * inv);
            pr[48] = (__bf16)(e3 * inv);
        }
    }
    __syncthreads();

    // P5: out = P @ V (A = P[n][m], B = vT[d][m]) -> ob [token][XP]
    for (int tt = wv; tt < 24; tt += 4) {
        int h = tt >> 3, mt = (tt >> 1) & 3, dt = tt & 1;
        const __bf16* pr = Pm + (h * 64 + mt * 16 + l15) * VP + quad * 8;
        const __bf16* vr = vT + (h * 32 + dt * 16 + l15) * VP + quad * 8;
        f32x4 acc = {0.f, 0.f, 0.f, 0.f};
        acc = MFMA16(*(const bf16x8*)(pr), *(const bf16x8*)(vr), acc);
        acc = MFMA16(*(const bf16x8*)(pr + 32), *(const bf16x8*)(vr + 32), acc);
        int col = h * 32 + dt * 16 + l15;
        #pragma unroll
        for (int r = 0; r < 4; r++) ob[(mt * 16 + quad * 4 + r) * XP + col] = (__bf16)acc[r];
    }
    __syncthreads();

    // P6: proj + scatter a = ob @ proj_wT + proj_b
    for (int tt = wv; tt < 24; tt += 4) {
        int mt = tt & 3, nt = tt >> 2;
        const __bf16* ar = ob + (mt * 16 + l15) * XP + quad * 8;
        const __bf16* br = wprojT + (size_t)(nt * 16 + l15) * 96 + quad * 8;
        f32x4 acc = {0.f, 0.f, 0.f, 0.f};
        #pragma unroll
        for (int ks = 0; ks < 3; ks++)
            acc = MFMA16(*(const bf16x8*)(ar + ks * 32), *(const bf16x8*)(br + ks * 32), acc);
        int col = nt * 16 + l15;
        float pb = projb[col];
        #pragma unroll
        for (int r = 0; r < 4; r++) {
            int row = mt * 16 + quad * 4 + r;
            if (row < 54) {
                int src = src_index(b, w, wh, ww, row);
                aout[(size_t)src * 96 + col] = acc[r] + pb;
            }
        }
    }
}

// ---------------- fused y = x + a; LN2; fc1+GELU; fc2; final = y + mlp (in-place on io) ----------------
// Barrier-free: each wave owns 16 tokens end-to-end. Per-wave LDS: xnw[16][104]bf16 (3328) +
// yw[16][100]f32 (6400) + sw[16][40]bf16 scratch (1280) = 11008 B; block total 44032 -> 3 blocks/CU.
__global__ __launch_bounds__(256, 3) void mlp_fused(const float* __restrict__ x,
                                                 const float* __restrict__ n2g, const float* __restrict__ n2b,
                                                 const float* __restrict__ fc1b, const float* __restrict__ fc2b,
                                                 const __bf16* __restrict__ w1T, const __bf16* __restrict__ w2T,
                                                 float* __restrict__ io)
{
    __shared__ __align__(16) char smem[44032];

    const int tid  = threadIdx.x;
    const int lane = tid & 63;
    const int wv   = tid >> 6;
    const int l15  = lane & 15;
    const int quad = lane >> 4;

    char* wbase = smem + wv * 11008;
    __bf16* xnw = (__bf16*)(wbase);          // [16][104] bf16
    float*  yw  = (float*)(wbase + 3328);    // [16][100] f32
    __bf16* sw  = (__bf16*)(wbase + 9728);   // [16][40]  bf16 C->A scratch

    const size_t t0 = (size_t)blockIdx.x * 64 + wv * 16;   // first token of this wave

    // Phase 1: y = x + a; LN2 -> xnw bf16, y -> yw f32.  4 tokens in parallel per iter.
    {
        const int c0 = l15 * 6;
        float g0 = n2g[c0], g1 = n2g[c0+1], g2 = n2g[c0+2], g3 = n2g[c0+3], g4 = n2g[c0+4], g5 = n2g[c0+5];
        float b0 = n2b[c0], b1 = n2b[c0+1], b2 = n2b[c0+2], b3 = n2b[c0+3], b4 = n2b[c0+4], b5 = n2b[c0+5];
        #pragma unroll
        for (int it = 0; it < 4; it++) {
            int row = it * 4 + quad;
            size_t base = (t0 + row) * 96 + c0;
            float2 x0 = *(const float2*)(x + base),     a0 = *(const float2*)(io + base);
            float2 x1 = *(const float2*)(x + base + 2), a1 = *(const float2*)(io + base + 2);
            float2 x2 = *(const float2*)(x + base + 4), a2 = *(const float2*)(io + base + 4);
            float y0 = x0.x + a0.x, y1 = x0.y + a0.y, y2 = x1.x + a1.x;
            float y3 = x1.y + a1.y, y4 = x2.x + a2.x, y5 = x2.y + a2.y;
            float s  = y0 + y1 + y2 + y3 + y4 + y5;
            float sq = y0*y0 + y1*y1 + y2*y2 + y3*y3 + y4*y4 + y5*y5;
            #pragma unroll
            for (int d = 1; d < 16; d <<= 1) { s += __shfl_xor(s, d, 16); sq += __shfl_xor(sq, d, 16); }
            float mean = s * (1.f / 96.f);
            float rstd = rsqrtf(sq * (1.f / 96.f) - mean * mean + 1e-5f);
            float* yr = yw + row * 100 + c0;
            yr[0] = y0; yr[1] = y1; yr[2] = y2; yr[3] = y3; yr[4] = y4; yr[5] = y5;
            __bf16* xr = xnw + row * XP + c0;
            xr[0] = (__bf16)((y0 - mean) * rstd * g0 + b0);
            xr[1] = (__bf16)((y1 - mean) * rstd * g1 + b1);
            xr[2] = (__bf16)((y2 - mean) * rstd * g2 + b2);
            xr[3] = (__bf16)((y3 - mean) * rstd * g3 + b3);
            xr[4] = (__bf16)((y4 - mean) * rstd * g4 + b4);
            xr[5] = (__bf16)((y5 - mean) * rstd * g5 + b5);
        }
    }
    // no barrier: wave-private LDS, in-wave LDS ordering is program order

    // Phase 2: fc1 + GELU; h kept in registers as fc2 A-fragments via per-wave scratch roundtrip
    bf16x8 afr[3];
    #pragma unroll
    for (int ks = 0; ks < 3; ks++)
        afr[ks] = *(const bf16x8*)(xnw + l15 * XP + ks * 32 + quad * 8);

    bf16x8 hfr[12];
    for (int nt = 0; nt < 24; nt++) {
        const __bf16* br = w1T + (size_t)(nt * 16 + l15) * 96 + quad * 8;
        f32x4 acc = {0.f, 0.f, 0.f, 0.f};
        #pragma unroll
        for (int ks = 0; ks < 3; ks++)
            acc = MFMA16(afr[ks], *(const bf16x8*)(br + ks * 32), acc);
        float fb = fc1b[nt * 16 + l15];
        #pragma unroll
        for (int r = 0; r < 4; r++) {
            float v = acc[r] + fb;
            float ge = 0.5f * v * (1.f + erff(v * 0.7071067811865475f));
            sw[(quad * 4 + r) * 40 + (nt & 1) * 16 + l15] = (__bf16)ge;
        }
        if (nt & 1)
            hfr[nt >> 1] = *(const bf16x8*)(sw + l15 * 40 + quad * 8);
    }

    // Phase 3: out = y + h @ fc2_wT + fc2_b (in-place)
    for (int nt = 0; nt < 6; nt++) {
        int col = nt * 16 + l15;
        const __bf16* br = w2T + (size_t)col * 384 + quad * 8;
        f32x4 acc = {0.f, 0.f, 0.f, 0.f};
        #pragma unroll
        for (int ks = 0; ks < 12; ks++)
            acc = MFMA16(hfr[ks], *(const bf16x8*)(br + ks * 32), acc);
        float fb = fc2b[col];
        #pragma unroll
        for (int r = 0; r < 4; r++) {
            int row = quad * 4 + r;
            io[(t0 + row) * 96 + col] = acc[r] + fb + yw[row * 100 + col];
        }
    }
}

extern "C" void kernel_launch(void* const* d_in, const int* in_sizes, int n_in,
                              void* d_out, int out_size, void* d_ws, size_t ws_size,
                              hipStream_t stream)
{
    const float* x      = (const float*)d_in[0];
    const float* n1g    = (const float*)d_in[1];
    const float* n1b    = (const float*)d_in[2];
    const float* qkv_w  = (const float*)d_in[3];
    const float* qkv_b  = (const float*)d_in[4];
    const float* rpb    = (const float*)d_in[5];
    const float* proj_w = (const float*)d_in[6];
    const float* proj_b = (const float*)d_in[7];
    const float* n2g    = (const float*)d_in[8];
    const float* n2b    = (const float*)d_in[9];
    const float* fc1_b  = (const float*)d_in[11];
    const float* fc1_w  = (const float*)d_in[10];
    const float* fc2_w  = (const float*)d_in[12];
    const float* fc2_b  = (const float*)d_in[13];

    __bf16* ws     = (__bf16*)d_ws;
    __bf16* wqkvT  = ws;            // [288][96]
    __bf16* wprojT = ws + 27648;    // [96][96]
    __bf16* w1T    = ws + 36864;    // [384][96]
    __bf16* w2T    = ws + 73728;    // [96][384]

    float* out = (float*)d_out;

    hipLaunchKernelGGL(wconv, dim3(432), dim3(256), 0, stream, qkv_w, proj_w, fc1_w, fc2_w, ws);
    hipLaunchKernelGGL(attn_fused, dim3(4096), dim3(256), 0, stream,
                       x, n1g, n1b, qkv_b, rpb, proj_b, wqkvT, wprojT, out);
    hipLaunchKernelGGL(mlp_fused, dim3(3456), dim3(256), 0, stream,
                       x, n2g, n2b, fc1_b, fc2_b, w1T, w2T, out);
}

// Round 4
// 506.114 us; speedup vs baseline: 1.7851x; 1.3867x over previous
//
#include <hip/hip_runtime.h>
#include <cmath>

typedef __bf16 bf16x8 __attribute__((ext_vector_type(8)));
typedef float  f32x4  __attribute__((ext_vector_type(4)));

#define MFMA16(a,b,c) __builtin_amdgcn_mfma_f32_16x16x32_bf16((a),(b),(c),0,0,0)

// DIM=96 NH=3 HEAD=32 WS=7 SHIFT=3 P=5 H=W=56 NWH=NWW=8 NW=64 TP=320 N=54 HIDDEN=384 B=64
#define SCALE_Q 0.17677669529663687f   // 32^-0.5

// LDS paddings: row-stride(dwords) % 32 == 20/4 -> <=2-way conflicts on b128
#define XP 104   // xn/ob row pad (bf16)
#define QP 296   // qkv row pad
#define VP 72    // vT/Pm row pad

// ---------------- weight convert: fp32 -> bf16, transposed to [n][k] ----------------
__global__ __launch_bounds__(256) void wconv(const float* __restrict__ qkv_w,
                                             const float* __restrict__ proj_w,
                                             const float* __restrict__ fc1_w,
                                             const float* __restrict__ fc2_w,
                                             __bf16* __restrict__ ws)
{
    int i = blockIdx.x * 256 + threadIdx.x;
    if (i < 27648) {                       // qkv_w (96,288) -> [c][k], fold q-scale
        int c = i / 96, k = i % 96;
        float v = qkv_w[k * 288 + c];
        if (c < 96) v *= SCALE_Q;
        ws[i] = (__bf16)v;
        return;
    }
    i -= 27648;
    if (i < 9216) {                        // proj_w (96,96)
        int c = i / 96, k = i % 96;
        ws[27648 + i] = (__bf16)proj_w[k * 96 + c];
        return;
    }
    i -= 9216;
    if (i < 36864) {                       // fc1_w (96,384)
        int c = i / 96, k = i % 96;
        ws[36864 + i] = (__bf16)fc1_w[k * 384 + c];
        return;
    }
    i -= 36864;
    if (i < 36864) {                       // fc2_w (384,96)
        int c = i / 384, k = i % 384;
        ws[73728 + i] = (__bf16)fc2_w[k * 96 + c];
    }
}

// ---------------- bias+mask table: [cls(2x2)][h(3)][n(64)][m(64)] fp32 ----------------
// cls = (wh==7)*2 + (ww==7). val = rpb bias + (-100 if cross-region) ; m>=54 -> -1e30
__global__ __launch_bounds__(256) void btab(const float* __restrict__ rpb, float* __restrict__ tbl)
{
    int i = blockIdx.x * 256 + threadIdx.x;   // < 49152
    if (i >= 49152) return;
    int m = i & 63;
    int n = (i >> 6) & 63;
    int h = (i >> 12) % 3;
    int cls = i / 12288;
    float v;
    if (m >= 54) {
        v = -1e30f;
    } else {
        v = 0.f;
        if (n >= 5 && n < 54 && m >= 5) {
            int an = n - 5, am = m - 5;
            int iy = an / 7, ix = an % 7, jy = am / 7, jx = am % 7;
            v = rpb[((iy - jy + 6) * 13 + (ix - jx + 6)) * 3 + h];
            int whp = cls >> 1, wwp = cls & 1;
            int idn = (whp ? (iy < 4 ? 1 : 2) : 0) * 3 + (wwp ? (ix < 4 ? 1 : 2) : 0);
            int idm = (whp ? (jy < 4 ? 1 : 2) : 0) * 3 + (wwp ? (jx < 4 ? 1 : 2) : 0);
            if (idn != idm) v -= 100.f;
        }
    }
    tbl[i] = v;
}

// token index in x for window token t of window (b, w=wh*8+ww); gather==scatter
__device__ __forceinline__ int src_index(int b, int w, int wh, int ww, int t)
{
    if (t < 5) return b * 3456 + w * 5 + t;
    int a = t - 5;
    int hi = wh * 7 + a / 7 + 3; if (hi >= 56) hi -= 56;
    int wi = ww * 7 + a % 7 + 3; if (wi >= 56) wi -= 56;
    return b * 3456 + 320 + hi * 56 + wi;
}

// ---------------- fused LN1 + window attention + proj; writes a (pre-residual) fp32 ----------------
__global__ __launch_bounds__(256, 2) void attn_fused(const float* __restrict__ x,
                                                  const float* __restrict__ n1g, const float* __restrict__ n1b,
                                                  const float* __restrict__ qkvb, const float* __restrict__ tbl,
                                                  const float* __restrict__ projb,
                                                  const __bf16* __restrict__ wqkvT, const __bf16* __restrict__ wprojT,
                                                  float* __restrict__ aout)
{
    __shared__ __align__(16) char smem[65024];
    __bf16* xn  = (__bf16*)(smem);           // [64][XP]   13312 B  (dead after P2)
    __bf16* qkv = (__bf16*)(smem + 13312);   // [64][QP]   37888 B  (dead after P3)
    __bf16* vT  = (__bf16*)(smem + 51200);   // [96][VP]   13824 B
    __bf16* Pm  = (__bf16*)(smem);           // [3][64][VP] 27648 B  aliases xn+qkv head (after P3)
    __bf16* ob  = (__bf16*)(smem + 27648);   // [64][XP]   13312 B  aliases dead qkv tail
    float*  obf = (float*)(smem);            // [64][100]  25600 B  aliases Pm (dead after P5)

    const int tid  = threadIdx.x;
    const int lane = tid & 63;
    const int wv   = tid >> 6;
    const int l15  = lane & 15;
    const int quad = lane >> 4;

    const int g  = blockIdx.x;
    const int b  = g >> 6;
    const int w  = g & 63;
    const int wh = w >> 3;
    const int ww = w & 7;

    // P0: zero pad rows 54..63 of xn
    for (int i = tid; i < 1040; i += 256) xn[54 * XP + i] = (__bf16)0.0f;

    // P1: gather + LN1, 4 tokens per wave-iteration (16-lane groups, 6 elems/lane)
    {
        const int c0 = l15 * 6;
        float g0 = n1g[c0], g1 = n1g[c0+1], g2 = n1g[c0+2], g3 = n1g[c0+3], g4 = n1g[c0+4], g5 = n1g[c0+5];
        float b0 = n1b[c0], b1 = n1b[c0+1], b2 = n1b[c0+2], b3 = n1b[c0+3], b4 = n1b[c0+4], b5 = n1b[c0+5];
        #pragma unroll
        for (int it = 0; it < 4; it++) {
            int t = it * 16 + wv * 4 + quad;
            if (t < 54) {
                int src = src_index(b, w, wh, ww, t);
                const float* xr = x + (size_t)src * 96 + c0;
                float2 v0 = *(const float2*)(xr);
                float2 v1 = *(const float2*)(xr + 2);
                float2 v2 = *(const float2*)(xr + 4);
                float s  = v0.x + v0.y + v1.x + v1.y + v2.x + v2.y;
                float sq = v0.x*v0.x + v0.y*v0.y + v1.x*v1.x + v1.y*v1.y + v2.x*v2.x + v2.y*v2.y;
                #pragma unroll
                for (int d = 1; d < 16; d <<= 1) { s += __shfl_xor(s, d, 16); sq += __shfl_xor(sq, d, 16); }
                float mean = s * (1.f / 96.f);
                float rstd = rsqrtf(sq * (1.f / 96.f) - mean * mean + 1e-5f);
                __bf16* xr2 = xn + t * XP + c0;
                xr2[0] = (__bf16)((v0.x - mean) * rstd * g0 + b0);
                xr2[1] = (__bf16)((v0.y - mean) * rstd * g1 + b1);
                xr2[2] = (__bf16)((v1.x - mean) * rstd * g2 + b2);
                xr2[3] = (__bf16)((v1.y - mean) * rstd * g3 + b3);
                xr2[4] = (__bf16)((v2.x - mean) * rstd * g4 + b4);
                xr2[5] = (__bf16)((v2.y - mean) * rstd * g5 + b5);
            }
        }
    }
    __syncthreads();

    // P2: QKV = xn(64x96) @ qkv_wT -> qkv [token][QP]; v also transposed into vT
    for (int tt = wv; tt < 72; tt += 4) {
        int mt = tt & 3, nt = tt >> 2;
        const __bf16* ar = xn + (mt * 16 + l15) * XP + quad * 8;
        const __bf16* br = wqkvT + (size_t)(nt * 16 + l15) * 96 + quad * 8;
        f32x4 acc = {0.f, 0.f, 0.f, 0.f};
        #pragma unroll
        for (int ks = 0; ks < 3; ks++)
            acc = MFMA16(*(const bf16x8*)(ar + ks * 32), *(const bf16x8*)(br + ks * 32), acc);
        int col = nt * 16 + l15;
        float bias = qkvb[col] * (col < 96 ? SCALE_Q : 1.f);
        #pragma unroll
        for (int r = 0; r < 4; r++) {
            int row = mt * 16 + quad * 4 + r;
            __bf16 bv = (__bf16)(acc[r] + bias);
            qkv[row * QP + col] = bv;
            if (col >= 192) vT[(col - 192) * VP + row] = bv;
        }
    }
    __syncthreads();

    // P3: scores S = q @ k^T + table(bias+mask) (registers, C-layout)
    const int cls = ((wh == 7) ? 2 : 0) + ((ww == 7) ? 1 : 0);
    const float* tbc = tbl + cls * 12288;
    float sc[3][4][4];
    #pragma unroll
    for (int p = 0; p < 3; p++) {
        int pid = wv + 4 * p;
        int h = pid >> 2, mt = pid & 3;
        bf16x8 aq = *(const bf16x8*)(qkv + (mt * 16 + l15) * QP + h * 32 + quad * 8);
        const float* tbh = tbc + h * 4096 + (mt * 16 + quad * 4) * 64 + l15;
        #pragma unroll
        for (int nt = 0; nt < 4; nt++) {
            bf16x8 bk = *(const bf16x8*)(qkv + (nt * 16 + l15) * QP + 96 + h * 32 + quad * 8);
            f32x4 c = {0.f, 0.f, 0.f, 0.f};
            c = MFMA16(aq, bk, c);
            #pragma unroll
            for (int r = 0; r < 4; r++)
                sc[p][nt][r] = c[r] + tbh[r * 64 + nt * 16];
        }
    }
    __syncthreads();   // q/k reads done; Pm may overwrite

    // P4: softmax across m (row in one quad-group), write P bf16
    #pragma unroll
    for (int p = 0; p < 3; p++) {
        int pid = wv + 4 * p;
        int h = pid >> 2, mt = pid & 3;
        #pragma unroll
        for (int r = 0; r < 4; r++) {
            float mx = fmaxf(fmaxf(sc[p][0][r], sc[p][1][r]), fmaxf(sc[p][2][r], sc[p][3][r]));
            #pragma unroll
            for (int d = 1; d < 16; d <<= 1) mx = fmaxf(mx, __shfl_xor(mx, d, 16));
            float e0 = __expf(sc[p][0][r] - mx), e1 = __expf(sc[p][1][r] - mx);
            float e2 = __expf(sc[p][2][r] - mx), e3 = __expf(sc[p][3][r] - mx);
            float sum = e0 + e1 + e2 + e3;
            #pragma unroll
            for (int d = 1; d < 16; d <<= 1) sum += __shfl_xor(sum, d, 16);
            float inv = 1.f / sum;
            int row = mt * 16 + quad * 4 + r;
            __bf16* pr = Pm + (h * 64 + row) * VP + l15;
            pr[0]  = (__bf16)(e0 * inv);
            pr[16] = (__bf16)(e1 * inv);
            pr[32] = (__bf16)(e2 * inv);
            pr[48] = (__bf16)(e3 * inv);
        }
    }
    __syncthreads();

    // P5: out = P @ V (A = P[n][m], B = vT[d][m]) -> ob [token][XP]
    for (int tt = wv; tt < 24; tt += 4) {
        int h = tt >> 3, mt = (tt >> 1) & 3, dt = tt & 1;
        const __bf16* pr = Pm + (h * 64 + mt * 16 + l15) * VP + quad * 8;
        const __bf16* vr = vT + (h * 32 + dt * 16 + l15) * VP + quad * 8;
        f32x4 acc = {0.f, 0.f, 0.f, 0.f};
        acc = MFMA16(*(const bf16x8*)(pr), *(const bf16x8*)(vr), acc);
        acc = MFMA16(*(const bf16x8*)(pr + 32), *(const bf16x8*)(vr + 32), acc);
        int col = h * 32 + dt * 16 + l15;
        #pragma unroll
        for (int r = 0; r < 4; r++) ob[(mt * 16 + quad * 4 + r) * XP + col] = (__bf16)acc[r];
    }
    __syncthreads();   // Pm dead; obf may overwrite

    // P6: proj -> obf fp32 [64][100]
    for (int tt = wv; tt < 24; tt += 4) {
        int mt = tt & 3, nt = tt >> 2;
        const __bf16* ar = ob + (mt * 16 + l15) * XP + quad * 8;
        const __bf16* br = wprojT + (size_t)(nt * 16 + l15) * 96 + quad * 8;
        f32x4 acc = {0.f, 0.f, 0.f, 0.f};
        #pragma unroll
        for (int ks = 0; ks < 3; ks++)
            acc = MFMA16(*(const bf16x8*)(ar + ks * 32), *(const bf16x8*)(br + ks * 32), acc);
        int col = nt * 16 + l15;
        float pb = projb[col];
        #pragma unroll
        for (int r = 0; r < 4; r++)
            obf[(mt * 16 + quad * 4 + r) * 100 + col] = acc[r] + pb;
    }
    __syncthreads();

    // P7: cooperative scatter, full 384B rows as float4 (54 rows x 24 float4)
    for (int i = tid; i < 1296; i += 256) {
        int row = i / 24, seg = i - row * 24;
        int src = src_index(b, w, wh, ww, row);
        const float* sp = obf + row * 100 + seg * 4;
        float4 v = make_float4(sp[0], sp[1], sp[2], sp[3]);
        *(float4*)(aout + (size_t)src * 96 + seg * 4) = v;
    }
}

// ---------------- fused y = x + a; LN2; fc1+GELU; fc2; final (in-place on io) ----------------
// Barrier-free: wave owns 16 tokens end-to-end, x/a loaded in A-frag layout, LN via quad shuffles.
// Per-wave LDS: sw[16][40]bf16 (1280) + swo[16][100]f32 (6400) = 7680 B; block 30720 B.
__global__ __launch_bounds__(256, 3) void mlp_fused(const float* __restrict__ x,
                                                 const float* __restrict__ n2g, const float* __restrict__ n2b,
                                                 const float* __restrict__ fc1b, const float* __restrict__ fc2b,
                                                 const __bf16* __restrict__ w1T, const __bf16* __restrict__ w2T,
                                                 float* __restrict__ io)
{
    __shared__ __align__(16) char smem[30720];

    const int tid  = threadIdx.x;
    const int lane = tid & 63;
    const int wv   = tid >> 6;
    const int l15  = lane & 15;
    const int quad = lane >> 4;

    char* wb = smem + wv * 7680;
    __bf16* sw  = (__bf16*)wb;           // [16][40]  bf16 C->A scratch
    float*  swo = (float*)(wb + 1280);   // [16][100] f32  y then final out

    const size_t t0 = (size_t)blockIdx.x * 64 + wv * 16;

    // Phase 1: y = x + a in A-frag layout (lane: token=l15, cols ks*32+quad*8+j); LN via quad shfl
    float yv[24];
    float s = 0.f, sq = 0.f;
    {
        const float* xr = x  + (t0 + l15) * 96 + quad * 8;
        const float* ar = io + (t0 + l15) * 96 + quad * 8;
        #pragma unroll
        for (int ks = 0; ks < 3; ks++) {
            float4 xa = *(const float4*)(xr + ks * 32);
            float4 xb = *(const float4*)(xr + ks * 32 + 4);
            float4 aa = *(const float4*)(ar + ks * 32);
            float4 ab = *(const float4*)(ar + ks * 32 + 4);
            float* yp = yv + ks * 8;
            yp[0] = xa.x + aa.x; yp[1] = xa.y + aa.y; yp[2] = xa.z + aa.z; yp[3] = xa.w + aa.w;
            yp[4] = xb.x + ab.x; yp[5] = xb.y + ab.y; yp[6] = xb.z + ab.z; yp[7] = xb.w + ab.w;
            #pragma unroll
            for (int j = 0; j < 8; j++) { s += yp[j]; sq += yp[j] * yp[j]; }
        }
    }
    s  += __shfl_xor(s, 16, 64);  sq += __shfl_xor(sq, 16, 64);
    s  += __shfl_xor(s, 32, 64);  sq += __shfl_xor(sq, 32, 64);
    float mean = s * (1.f / 96.f);
    float rstd = rsqrtf(sq * (1.f / 96.f) - mean * mean + 1e-5f);

    bf16x8 afr[3];
    #pragma unroll
    for (int ks = 0; ks < 3; ks++) {
        float4 g0 = *(const float4*)(n2g + ks * 32 + quad * 8);
        float4 g1 = *(const float4*)(n2g + ks * 32 + quad * 8 + 4);
        float4 b0 = *(const float4*)(n2b + ks * 32 + quad * 8);
        float4 b1 = *(const float4*)(n2b + ks * 32 + quad * 8 + 4);
        float gg[8] = {g0.x,g0.y,g0.z,g0.w,g1.x,g1.y,g1.z,g1.w};
        float bb[8] = {b0.x,b0.y,b0.z,b0.w,b1.x,b1.y,b1.z,b1.w};
        #pragma unroll
        for (int j = 0; j < 8; j++)
            afr[ks][j] = (__bf16)((yv[ks*8+j] - mean) * rstd * gg[j] + bb[j]);
        float* sp = swo + l15 * 100 + ks * 32 + quad * 8;
        sp[0] = yv[ks*8+0]; sp[1] = yv[ks*8+1]; sp[2] = yv[ks*8+2]; sp[3] = yv[ks*8+3];
        sp[4] = yv[ks*8+4]; sp[5] = yv[ks*8+5]; sp[6] = yv[ks*8+6]; sp[7] = yv[ks*8+7];
    }

    // Phase 2: fc1 + fast GELU; h -> fc2 A-fragments via per-wave scratch roundtrip
    bf16x8 hfr[12];
    for (int np = 0; np < 12; np++) {
        #pragma unroll
        for (int u = 0; u < 2; u++) {
            int ntx = np * 2 + u;
            const __bf16* br = w1T + (size_t)(ntx * 16 + l15) * 96 + quad * 8;
            f32x4 acc = {0.f, 0.f, 0.f, 0.f};
            #pragma unroll
            for (int ks = 0; ks < 3; ks++)
                acc = MFMA16(afr[ks], *(const bf16x8*)(br + ks * 32), acc);
            float fb = fc1b[ntx * 16 + l15];
            #pragma unroll
            for (int r = 0; r < 4; r++) {
                float v  = acc[r] + fb;
                float u2 = -1.5957691216057308f * v * (1.f + 0.044715f * v * v);
                float t  = __expf(u2);
                float ge = v * __builtin_amdgcn_rcpf(1.f + t);
                sw[(quad * 4 + r) * 40 + u * 16 + l15] = (__bf16)ge;
            }
        }
        hfr[np] = *(const bf16x8*)(sw + l15 * 40 + quad * 8);
    }

    // Phase 3: swo += h @ fc2_wT + fc2_b   (swo holds y -> becomes final)
    for (int nt = 0; nt < 6; nt++) {
        int col = nt * 16 + l15;
        const __bf16* br = w2T + (size_t)col * 384 + quad * 8;
        f32x4 acc = {0.f, 0.f, 0.f, 0.f};
        #pragma unroll
        for (int ks = 0; ks < 12; ks++)
            acc = MFMA16(hfr[ks], *(const bf16x8*)(br + ks * 32), acc);
        float fb = fc2b[col];
        #pragma unroll
        for (int r = 0; r < 4; r++) {
            int row = quad * 4 + r;
            swo[row * 100 + col] += acc[r] + fb;
        }
    }

    // Phase 4: contiguous write-out (wave's 16 tokens = 6144 B linear)
    #pragma unroll
    for (int it = 0; it < 6; it++) {
        int j = it * 256 + lane * 4;
        int row = j / 96, c = j - row * 96;
        const float* sp = swo + row * 100 + c;
        float4 v = make_float4(sp[0], sp[1], sp[2], sp[3]);
        *(float4*)(io + (t0 + row) * 96 + c) = v;
    }
}

extern "C" void kernel_launch(void* const* d_in, const int* in_sizes, int n_in,
                              void* d_out, int out_size, void* d_ws, size_t ws_size,
                              hipStream_t stream)
{
    const float* x      = (const float*)d_in[0];
    const float* n1g    = (const float*)d_in[1];
    const float* n1b    = (const float*)d_in[2];
    const float* qkv_w  = (const float*)d_in[3];
    const float* qkv_b  = (const float*)d_in[4];
    const float* rpb    = (const float*)d_in[5];
    const float* proj_w = (const float*)d_in[6];
    const float* proj_b = (const float*)d_in[7];
    const float* n2g    = (const float*)d_in[8];
    const float* n2b    = (const float*)d_in[9];
    const float* fc1_w  = (const float*)d_in[10];
    const float* fc1_b  = (const float*)d_in[11];
    const float* fc2_w  = (const float*)d_in[12];
    const float* fc2_b  = (const float*)d_in[13];

    __bf16* ws     = (__bf16*)d_ws;
    __bf16* wqkvT  = ws;            // [288][96]
    __bf16* wprojT = ws + 27648;    // [96][96]
    __bf16* w1T    = ws + 36864;    // [384][96]
    __bf16* w2T    = ws + 73728;    // [96][384]
    float*  tbl    = (float*)((char*)d_ws + 221184);   // [4][3][64][64] fp32, 196608 B

    float* out = (float*)d_out;

    hipLaunchKernelGGL(wconv, dim3(432), dim3(256), 0, stream, qkv_w, proj_w, fc1_w, fc2_w, ws);
    hipLaunchKernelGGL(btab,  dim3(192), dim3(256), 0, stream, rpb, tbl);
    hipLaunchKernelGGL(attn_fused, dim3(4096), dim3(256), 0, stream,
                       x, n1g, n1b, qkv_b, tbl, proj_b, wqkvT, wprojT, out);
    hipLaunchKernelGGL(mlp_fused, dim3(3456), dim3(256), 0, stream,
                       x, n2g, n2b, fc1_b, fc2_b, w1T, w2T, out);
}

// Round 5
// 480.020 us; speedup vs baseline: 1.8821x; 1.0544x over previous
//
#include <hip/hip_runtime.h>
#include <cmath>

typedef __bf16 bf16x8 __attribute__((ext_vector_type(8)));
typedef float  f32x4  __attribute__((ext_vector_type(4)));

#define MFMA16(a,b,c) __builtin_amdgcn_mfma_f32_16x16x32_bf16((a),(b),(c),0,0,0)

// DIM=96 NH=3 HEAD=32 WS=7 SHIFT=3 P=5 H=W=56 NWH=NWW=8 NW=64 TP=320 N=54 HIDDEN=384 B=64
#define SCALE_Q 0.17677669529663687f   // 32^-0.5

// LDS strides (bf16 elems); dword-stride mod 32 in {20,4,2} -> <=2-way (free) b128 conflicts
#define XP 104   // xn/ob: 52 dw % 32 = 20
#define KQP 200  // qkv(q,k): 100 dw % 32 = 4
#define VP 68    // vT/Pm: 34 dw % 32 = 2

// ---------------- weight convert: fp32 -> bf16, transposed to [n][k] ----------------
__global__ __launch_bounds__(256) void wconv(const float* __restrict__ qkv_w,
                                             const float* __restrict__ proj_w,
                                             const float* __restrict__ fc1_w,
                                             const float* __restrict__ fc2_w,
                                             __bf16* __restrict__ ws)
{
    int i = blockIdx.x * 256 + threadIdx.x;
    if (i < 27648) {                       // qkv_w (96,288) -> [c][k], fold q-scale
        int c = i / 96, k = i % 96;
        float v = qkv_w[k * 288 + c];
        if (c < 96) v *= SCALE_Q;
        ws[i] = (__bf16)v;
        return;
    }
    i -= 27648;
    if (i < 9216) {                        // proj_w (96,96)
        int c = i / 96, k = i % 96;
        ws[27648 + i] = (__bf16)proj_w[k * 96 + c];
        return;
    }
    i -= 9216;
    if (i < 36864) {                       // fc1_w (96,384)
        int c = i / 96, k = i % 96;
        ws[36864 + i] = (__bf16)fc1_w[k * 384 + c];
        return;
    }
    i -= 36864;
    if (i < 36864) {                       // fc2_w (384,96)
        int c = i / 384, k = i % 384;
        ws[73728 + i] = (__bf16)fc2_w[k * 96 + c];
    }
}

// ---------------- bias+mask table: [cls(2x2)][h(3)][n(64)][m(64)] fp32 ----------------
__global__ __launch_bounds__(256) void btab(const float* __restrict__ rpb, float* __restrict__ tbl)
{
    int i = blockIdx.x * 256 + threadIdx.x;   // < 49152
    if (i >= 49152) return;
    int m = i & 63;
    int n = (i >> 6) & 63;
    int h = (i >> 12) % 3;
    int cls = i / 12288;
    float v;
    if (m >= 54) {
        v = -1e30f;
    } else {
        v = 0.f;
        if (n >= 5 && n < 54 && m >= 5) {
            int an = n - 5, am = m - 5;
            int iy = an / 7, ix = an % 7, jy = am / 7, jx = am % 7;
            v = rpb[((iy - jy + 6) * 13 + (ix - jx + 6)) * 3 + h];
            int whp = cls >> 1, wwp = cls & 1;
            int idn = (whp ? (iy < 4 ? 1 : 2) : 0) * 3 + (wwp ? (ix < 4 ? 1 : 2) : 0);
            int idm = (whp ? (jy < 4 ? 1 : 2) : 0) * 3 + (wwp ? (jx < 4 ? 1 : 2) : 0);
            if (idn != idm) v -= 100.f;
        }
    }
    tbl[i] = v;
}

// token index in x for window token t of window (b, w=wh*8+ww); gather==scatter
__device__ __forceinline__ int src_index(int b, int w, int wh, int ww, int t)
{
    if (t < 5) return b * 3456 + w * 5 + t;
    int a = t - 5;
    int hi = wh * 7 + a / 7 + 3; if (hi >= 56) hi -= 56;
    int wi = ww * 7 + a % 7 + 3; if (wi >= 56) wi -= 56;
    return b * 3456 + 320 + hi * 56 + wi;
}

// ============ fully fused transformer block: LN1+attn+proj+residual+LN2+MLP+residual ============
// One block per window. LDS 52480 B -> 3 blocks/CU.
__global__ __launch_bounds__(256, 3) void block_fused(const float* __restrict__ x,
                                                  const float* __restrict__ n1g, const float* __restrict__ n1b,
                                                  const float* __restrict__ qkvb, const float* __restrict__ tbl,
                                                  const float* __restrict__ projb,
                                                  const float* __restrict__ n2g, const float* __restrict__ n2b,
                                                  const float* __restrict__ fc1b, const float* __restrict__ fc2b,
                                                  const __bf16* __restrict__ wqkvT, const __bf16* __restrict__ wprojT,
                                                  const __bf16* __restrict__ w1T, const __bf16* __restrict__ w2T,
                                                  float* __restrict__ out)
{
    __shared__ __align__(16) char smem[52480];
    __bf16* xn  = (__bf16*)(smem);           // [64][XP]    13312 B  (P0-P2)
    __bf16* qkv = (__bf16*)(smem + 13312);   // [64][KQP]   25600 B  q:0-95 k:96-191 (P2-P3)
    __bf16* Pm  = (__bf16*)(smem);           // [3][64][VP] 26112 B  (P4-P5, aliases xn+qkv head)
    __bf16* ob  = (__bf16*)(smem + 26112);   // [64][XP]    13312 B  (P5-P6, aliases qkv tail)
    __bf16* vT  = (__bf16*)(smem + 39424);   // [96][VP]    13056 B  (P2-P5)
    float*  obf = (float*)(smem);            // [64][100]   25600 B  a -> y -> final (P6-end)
    __bf16* sws = (__bf16*)(smem + 39424);   // per-wave [16][40] scratch in dead vT (MLP)

    const int tid  = threadIdx.x;
    const int lane = tid & 63;
    const int wv   = tid >> 6;
    const int l15  = lane & 15;
    const int quad = lane >> 4;

    const int g  = blockIdx.x;
    const int b  = g >> 6;
    const int w  = g & 63;
    const int wh = w >> 3;
    const int ww = w & 7;

    // P0: zero pad rows 54..63 of xn
    for (int i = tid; i < 1040; i += 256) xn[54 * XP + i] = (__bf16)0.0f;

    // P1: gather + LN1, 4 tokens per wave-iteration (16-lane groups, 6 elems/lane)
    {
        const int c0 = l15 * 6;
        float g0 = n1g[c0], g1 = n1g[c0+1], g2 = n1g[c0+2], g3 = n1g[c0+3], g4 = n1g[c0+4], g5 = n1g[c0+5];
        float b0 = n1b[c0], b1 = n1b[c0+1], b2 = n1b[c0+2], b3 = n1b[c0+3], b4 = n1b[c0+4], b5 = n1b[c0+5];
        #pragma unroll
        for (int it = 0; it < 4; it++) {
            int t = it * 16 + wv * 4 + quad;
            if (t < 54) {
                int src = src_index(b, w, wh, ww, t);
                const float* xr = x + (size_t)src * 96 + c0;
                float2 v0 = *(const float2*)(xr);
                float2 v1 = *(const float2*)(xr + 2);
                float2 v2 = *(const float2*)(xr + 4);
                float s  = v0.x + v0.y + v1.x + v1.y + v2.x + v2.y;
                float sq = v0.x*v0.x + v0.y*v0.y + v1.x*v1.x + v1.y*v1.y + v2.x*v2.x + v2.y*v2.y;
                #pragma unroll
                for (int d = 1; d < 16; d <<= 1) { s += __shfl_xor(s, d, 16); sq += __shfl_xor(sq, d, 16); }
                float mean = s * (1.f / 96.f);
                float rstd = rsqrtf(sq * (1.f / 96.f) - mean * mean + 1e-5f);
                __bf16* xr2 = xn + t * XP + c0;
                xr2[0] = (__bf16)((v0.x - mean) * rstd * g0 + b0);
                xr2[1] = (__bf16)((v0.y - mean) * rstd * g1 + b1);
                xr2[2] = (__bf16)((v1.x - mean) * rstd * g2 + b2);
                xr2[3] = (__bf16)((v1.y - mean) * rstd * g3 + b3);
                xr2[4] = (__bf16)((v2.x - mean) * rstd * g4 + b4);
                xr2[5] = (__bf16)((v2.y - mean) * rstd * g5 + b5);
            }
        }
    }
    __syncthreads();

    // P2: QKV = xn(64x96) @ qkv_wT ; q,k -> qkv tile, v -> vT (transposed)
    for (int tt = wv; tt < 72; tt += 4) {
        int mt = tt & 3, nt = tt >> 2;
        const __bf16* ar = xn + (mt * 16 + l15) * XP + quad * 8;
        const __bf16* br = wqkvT + (size_t)(nt * 16 + l15) * 96 + quad * 8;
        f32x4 acc = {0.f, 0.f, 0.f, 0.f};
        #pragma unroll
        for (int ks = 0; ks < 3; ks++)
            acc = MFMA16(*(const bf16x8*)(ar + ks * 32), *(const bf16x8*)(br + ks * 32), acc);
        int col = nt * 16 + l15;
        float bias = qkvb[col] * (col < 96 ? SCALE_Q : 1.f);
        #pragma unroll
        for (int r = 0; r < 4; r++) {
            int row = mt * 16 + quad * 4 + r;
            __bf16 bv = (__bf16)(acc[r] + bias);
            if (col < 192) qkv[row * KQP + col] = bv;
            else           vT[(col - 192) * VP + row] = bv;
        }
    }
    __syncthreads();

    // P3: scores S = q @ k^T + table(bias+mask) (registers, C-layout)
    const int cls = ((wh == 7) ? 2 : 0) + ((ww == 7) ? 1 : 0);
    const float* tbc = tbl + cls * 12288;
    float sc[3][4][4];
    #pragma unroll
    for (int p = 0; p < 3; p++) {
        int pid = wv + 4 * p;
        int h = pid >> 2, mt = pid & 3;
        bf16x8 aq = *(const bf16x8*)(qkv + (mt * 16 + l15) * KQP + h * 32 + quad * 8);
        const float* tbh = tbc + h * 4096 + (mt * 16 + quad * 4) * 64 + l15;
        #pragma unroll
        for (int nt = 0; nt < 4; nt++) {
            bf16x8 bk = *(const bf16x8*)(qkv + (nt * 16 + l15) * KQP + 96 + h * 32 + quad * 8);
            f32x4 c = {0.f, 0.f, 0.f, 0.f};
            c = MFMA16(aq, bk, c);
            #pragma unroll
            for (int r = 0; r < 4; r++)
                sc[p][nt][r] = c[r] + tbh[r * 64 + nt * 16];
        }
    }
    __syncthreads();   // q/k reads done; Pm may overwrite

    // P4: softmax across m, write P bf16
    #pragma unroll
    for (int p = 0; p < 3; p++) {
        int pid = wv + 4 * p;
        int h = pid >> 2, mt = pid & 3;
        #pragma unroll
        for (int r = 0; r < 4; r++) {
            float mx = fmaxf(fmaxf(sc[p][0][r], sc[p][1][r]), fmaxf(sc[p][2][r], sc[p][3][r]));
            #pragma unroll
            for (int d = 1; d < 16; d <<= 1) mx = fmaxf(mx, __shfl_xor(mx, d, 16));
            float e0 = __expf(sc[p][0][r] - mx), e1 = __expf(sc[p][1][r] - mx);
            float e2 = __expf(sc[p][2][r] - mx), e3 = __expf(sc[p][3][r] - mx);
            float sum = e0 + e1 + e2 + e3;
            #pragma unroll
            for (int d = 1; d < 16; d <<= 1) sum += __shfl_xor(sum, d, 16);
            float inv = 1.f / sum;
            int row = mt * 16 + quad * 4 + r;
            __bf16* pr = Pm + (h * 64 + row) * VP + l15;
            pr[0]  = (__bf16)(e0 * inv);
            pr[16] = (__bf16)(e1 * inv);
            pr[32] = (__bf16)(e2 * inv);
            pr[48] = (__bf16)(e3 * inv);
        }
    }
    __syncthreads();

    // P5: out = P @ V (A = P[n][m], B = vT[d][m]) -> ob [token][XP]
    for (int tt = wv; tt < 24; tt += 4) {
        int h = tt >> 3, mt = (tt >> 1) & 3, dt = tt & 1;
        const __bf16* pr = Pm + (h * 64 + mt * 16 + l15) * VP + quad * 8;
        const __bf16* vr = vT + (h * 32 + dt * 16 + l15) * VP + quad * 8;
        f32x4 acc = {0.f, 0.f, 0.f, 0.f};
        acc = MFMA16(*(const bf16x8*)(pr), *(const bf16x8*)(vr), acc);
        acc = MFMA16(*(const bf16x8*)(pr + 32), *(const bf16x8*)(vr + 32), acc);
        int col = h * 32 + dt * 16 + l15;
        #pragma unroll
        for (int r = 0; r < 4; r++) ob[(mt * 16 + quad * 4 + r) * XP + col] = (__bf16)acc[r];
    }
    __syncthreads();   // Pm/vT dead; obf + per-wave scratch live from here. LAST barrier.

    // P6: proj -> obf fp32 [64][100]; wave wv computes exactly rows [wv*16, wv*16+16)
    for (int nt = 0; nt < 6; nt++) {
        const __bf16* ar = ob + (wv * 16 + l15) * XP + quad * 8;
        const __bf16* br = wprojT + (size_t)(nt * 16 + l15) * 96 + quad * 8;
        f32x4 acc = {0.f, 0.f, 0.f, 0.f};
        #pragma unroll
        for (int ks = 0; ks < 3; ks++)
            acc = MFMA16(*(const bf16x8*)(ar + ks * 32), *(const bf16x8*)(br + ks * 32), acc);
        int col = nt * 16 + l15;
        float pb = projb[col];
        #pragma unroll
        for (int r = 0; r < 4; r++)
            obf[(wv * 16 + quad * 4 + r) * 100 + col] = acc[r] + pb;
    }
    // NOTE: ob rows [wv*16, wv*16+16) were written in P5 by multiple waves -- but the P5 barrier
    // already ordered them. After P6 everything is wave-private: no more __syncthreads needed.

    // M1: y = x + a (A-frag layout: token=l15, cols ks*32+quad*8+j); LN2 via quad shuffles
    const int arow = wv * 16 + l15;
    const int asrc = src_index(b, w, wh, ww, arow < 54 ? arow : 53);
    float yv[24];
    float s = 0.f, sq = 0.f;
    {
        const float* xr = x + (size_t)asrc * 96 + quad * 8;
        #pragma unroll
        for (int ks = 0; ks < 3; ks++) {
            float4 xa = *(const float4*)(xr + ks * 32);
            float4 xb = *(const float4*)(xr + ks * 32 + 4);
            float* ap = obf + arow * 100 + ks * 32 + quad * 8;
            float* yp = yv + ks * 8;
            yp[0] = xa.x + ap[0]; yp[1] = xa.y + ap[1]; yp[2] = xa.z + ap[2]; yp[3] = xa.w + ap[3];
            yp[4] = xb.x + ap[4]; yp[5] = xb.y + ap[5]; yp[6] = xb.z + ap[6]; yp[7] = xb.w + ap[7];
            #pragma unroll
            for (int j = 0; j < 8; j++) { s += yp[j]; sq += yp[j] * yp[j]; }
            // park y back into obf (wave-private rows; in-wave lgkmcnt ordering)
            ap[0] = yp[0]; ap[1] = yp[1]; ap[2] = yp[2]; ap[3] = yp[3];
            ap[4] = yp[4]; ap[5] = yp[5]; ap[6] = yp[6]; ap[7] = yp[7];
        }
    }
    s  += __shfl_xor(s, 16, 64);  sq += __shfl_xor(sq, 16, 64);
    s  += __shfl_xor(s, 32, 64);  sq += __shfl_xor(sq, 32, 64);
    float mean = s * (1.f / 96.f);
    float rstd = rsqrtf(sq * (1.f / 96.f) - mean * mean + 1e-5f);

    bf16x8 afr[3];
    #pragma unroll
    for (int ks = 0; ks < 3; ks++) {
        float4 g0 = *(const float4*)(n2g + ks * 32 + quad * 8);
        float4 g1 = *(const float4*)(n2g + ks * 32 + quad * 8 + 4);
        float4 b0 = *(const float4*)(n2b + ks * 32 + quad * 8);
        float4 b1 = *(const float4*)(n2b + ks * 32 + quad * 8 + 4);
        float gg[8] = {g0.x,g0.y,g0.z,g0.w,g1.x,g1.y,g1.z,g1.w};
        float bb[8] = {b0.x,b0.y,b0.z,b0.w,b1.x,b1.y,b1.z,b1.w};
        #pragma unroll
        for (int j = 0; j < 8; j++)
            afr[ks][j] = (__bf16)((yv[ks*8+j] - mean) * rstd * gg[j] + bb[j]);
    }

    // M2: fc1 + fast GELU; h -> fc2 A-fragments via per-wave scratch roundtrip
    __bf16* sw = sws + wv * 640;     // [16][40] bf16 = 1280 B per wave
    bf16x8 hfr[12];
    for (int np = 0; np < 12; np++) {
        #pragma unroll
        for (int u = 0; u < 2; u++) {
            int ntx = np * 2 + u;
            const __bf16* br = w1T + (size_t)(ntx * 16 + l15) * 96 + quad * 8;
            f32x4 acc = {0.f, 0.f, 0.f, 0.f};
            #pragma unroll
            for (int ks = 0; ks < 3; ks++)
                acc = MFMA16(afr[ks], *(const bf16x8*)(br + ks * 32), acc);
            float fb = fc1b[ntx * 16 + l15];
            #pragma unroll
            for (int r = 0; r < 4; r++) {
                float v  = acc[r] + fb;
                float u2 = -1.5957691216057308f * v * (1.f + 0.044715f * v * v);
                float t  = __expf(u2);
                float ge = v * __builtin_amdgcn_rcpf(1.f + t);
                sw[(quad * 4 + r) * 40 + u * 16 + l15] = (__bf16)ge;
            }
        }
        hfr[np] = *(const bf16x8*)(sw + l15 * 40 + quad * 8);
    }

    // M3: obf(=y) += h @ fc2_wT + fc2_b  (wave-private rows)
    for (int nt = 0; nt < 6; nt++) {
        int col = nt * 16 + l15;
        const __bf16* br = w2T + (size_t)col * 384 + quad * 8;
        f32x4 acc = {0.f, 0.f, 0.f, 0.f};
        #pragma unroll
        for (int ks = 0; ks < 12; ks++)
            acc = MFMA16(hfr[ks], *(const bf16x8*)(br + ks * 32), acc);
        float fb = fc2b[col];
        #pragma unroll
        for (int r = 0; r < 4; r++)
            obf[(wv * 16 + quad * 4 + r) * 100 + col] += acc[r] + fb;
    }

    // M4: scatter final rows (full 384 B granules; wave-private rows -> no barrier)
    #pragma unroll
    for (int it = 0; it < 6; it++) {
        int i = it * 64 + lane;          // < 384
        int rr = i / 24, seg = i - rr * 24;
        int row = wv * 16 + rr;
        if (row < 54) {
            int src = src_index(b, w, wh, ww, row);
            const float* sp = obf + row * 100 + seg * 4;
            float4 v = make_float4(sp[0], sp[1], sp[2], sp[3]);
            *(float4*)(out + (size_t)src * 96 + seg * 4) = v;
        }
    }
}

extern "C" void kernel_launch(void* const* d_in, const int* in_sizes, int n_in,
                              void* d_out, int out_size, void* d_ws, size_t ws_size,
                              hipStream_t stream)
{
    const float* x      = (const float*)d_in[0];
    const float* n1g    = (const float*)d_in[1];
    const float* n1b    = (const float*)d_in[2];
    const float* qkv_w  = (const float*)d_in[3];
    const float* qkv_b  = (const float*)d_in[4];
    const float* rpb    = (const float*)d_in[5];
    const float* proj_w = (const float*)d_in[6];
    const float* proj_b = (const float*)d_in[7];
    const float* n2g    = (const float*)d_in[8];
    const float* n2b    = (const float*)d_in[9];
    const float* fc1_w  = (const float*)d_in[10];
    const float* fc1_b  = (const float*)d_in[11];
    const float* fc2_w  = (const float*)d_in[12];
    const float* fc2_b  = (const float*)d_in[13];

    __bf16* ws     = (__bf16*)d_ws;
    __bf16* wqkvT  = ws;            // [288][96]
    __bf16* wprojT = ws + 27648;    // [96][96]
    __bf16* w1T    = ws + 36864;    // [384][96]
    __bf16* w2T    = ws + 73728;    // [96][384]
    float*  tbl    = (float*)((char*)d_ws + 221184);   // [4][3][64][64] fp32, 196608 B

    float* out = (float*)d_out;

    hipLaunchKernelGGL(wconv, dim3(432), dim3(256), 0, stream, qkv_w, proj_w, fc1_w, fc2_w, ws);
    hipLaunchKernelGGL(btab,  dim3(192), dim3(256), 0, stream, rpb, tbl);
    hipLaunchKernelGGL(block_fused, dim3(4096), dim3(256), 0, stream,
                       x, n1g, n1b, qkv_b, tbl, proj_b, n2g, n2b, fc1_b, fc2_b,
                       wqkvT, wprojT, w1T, w2T, out);
}